// Round 17
// baseline (554.164 us; speedup 1.0000x reference)
//
#include <hip/hip_runtime.h>
#include <hip/hip_bf16.h>
#include <hip/hip_fp16.h>
#include <math.h>

#define DEVI __device__ __forceinline__

typedef _Float16 f16;
typedef f16 f16x2 __attribute__((ext_vector_type(2)));
typedef f16 f16x4 __attribute__((ext_vector_type(4)));
typedef f16 f16x8 __attribute__((ext_vector_type(8)));
typedef float f32x4 __attribute__((ext_vector_type(4)));

// ---- problem dims (fixed) ----
constexpr int Bb = 2, Hh = 32, Ww = 32, Dd = 32;
constexpr int Nn = Hh * Ww * Dd;      // 32768
constexpr int BN = Bb * Nn;           // 65536 tokens
constexpr int CIN = 160, CHH = 640;
constexpr int PD = 34;                // padded dim
constexpr int PT = PD * PD * PD;      // 39304 padded tokens per batch

// ---- workspace layout (bytes) ----
constexpr size_t W1_OFF  = 0;                                   // fc1_w f16: 204,800
constexpr size_t W2_OFF  = W1_OFF + (size_t)CHH * CIN * 2;      // fc2_w f16: 204,800
constexpr size_t WTH_OFF = W2_OFF + (size_t)CIN * CHH * 2;      // dw_w f16 [27][640]: 34,560
constexpr size_t ZP_OFF  = WTH_OFF + 34816;                     // zero page: 8,192
constexpr size_t U_OFF   = 458752;                              // h2 f16: 83,886,080
constexpr size_t H1P_OFF = U_OFF + (size_t)BN * CHH * 2;        // h1 padded f16: 100,618,240

DEVI void async16(const void* g, void* l) {
  __builtin_amdgcn_global_load_lds(
      (const __attribute__((address_space(1))) void*)g,
      (__attribute__((address_space(3))) void*)l, 16, 0, 0);
}

// packed-f16 GELU (tanh form, div-free): g = x - x * rcp(1 + exp2(x*(C1+C2*x^2)))
DEVI f16x8 gelu8(f16x8 xa) {
  const __half2 C1 = __float2half2_rn(2.3022078f);
  const __half2 C2 = __float2half2_rn(0.102943324f);
  const __half2 ONE = __float2half2_rn(1.0f);
  f16x8 out;
#pragma unroll
  for (int j = 0; j < 8; j += 2) {
    __half2 xv = __builtin_bit_cast(__half2, f16x2{xa[j], xa[j + 1]});
    __half2 x2 = __hmul2(xv, xv);
    __half2 t  = __hfma2(x2, C2, C1);
    __half2 u  = __hmul2(xv, t);
    __half2 e  = h2exp2(u);
    __half2 r  = h2rcp(__hadd2(e, ONE));
    __half2 g  = __hsub2(xv, __hmul2(xv, r));
    f16x2 gg = __builtin_bit_cast(f16x2, g);
    out[j] = gg[0]; out[j + 1] = gg[1];
  }
  return out;
}

// ---- prep (merged): weights -> f16, dw transpose, zero page, h1p shell faces ----
constexpr int PREPW_BLOCKS = 876;                       // 2*NW + 27*CHH + 2048
constexpr int NSHELL = 13072;                           // shell tokens total
constexpr int SHELL_BLOCKS = (NSHELL * 80 + 255) / 256; // 4085

__global__ __launch_bounds__(256) void k_prep(const float* __restrict__ fc1w,
                                              const float* __restrict__ fc2w,
                                              const float* __restrict__ dww,
                                              f16* __restrict__ w1h,
                                              f16* __restrict__ w2h,
                                              f16* __restrict__ wTh,
                                              unsigned* __restrict__ zp,
                                              f16* __restrict__ h1p) {
  const int bid = blockIdx.x;
  const int tid = threadIdx.x;
  if (bid < PREPW_BLOCKS) {
    int i = bid * 256 + tid;
    const int NW = CHH * CIN;  // 102400
    if (i < NW) {
      w1h[i] = (f16)fc1w[i];
    } else if (i < 2 * NW) {
      w2h[i - NW] = (f16)fc2w[i - NW];
    } else if (i < 2 * NW + 27 * CHH) {
      int j = i - 2 * NW;
      int ch = j / 27, tap = j % 27;
      wTh[tap * CHH + ch] = (f16)dww[j];
    } else if (i < 2 * NW + 27 * CHH + 2048) {
      zp[i - (2 * NW + 27 * CHH)] = 0u;
    }
    return;
  }
  // shell faces: thread per (shell token, 8-ch chunk), chunk fastest -> coalesced
  int g = (bid - PREPW_BLOCKS) * 256 + tid;
  int t = g / 80;
  int c = g - t * 80;
  if (t >= NSHELL) return;
  int b, hp, wp, dp;
  if (t < 4624) {                     // hp faces: [2][2][34][34]
    int i = t;
    b = i / 2312; i -= b * 2312;
    int f = i / 1156; i -= f * 1156;
    hp = f ? PD - 1 : 0;
    wp = i / 34; dp = i - (i / 34) * 34;
  } else if (t < 8976) {              // wp faces: [2][2][32][34], hp interior
    int i = t - 4624;
    b = i / 2176; i -= b * 2176;
    int f = i / 1088; i -= f * 1088;
    wp = f ? PD - 1 : 0;
    hp = 1 + i / 34; dp = i - (i / 34) * 34;
  } else {                            // dp faces: [2][2][32][32], hp,wp interior
    int i = t - 8976;
    b = i / 2048; i -= b * 2048;
    int f = i / 1024; i -= f * 1024;
    dp = f ? PD - 1 : 0;
    hp = 1 + i / 32; wp = 1 + (i & 31);
  }
  size_t p = ((size_t)(b * PD + hp) * PD + wp) * PD + dp;
  f16x8 z = {};
  *(f16x8*)&h1p[p * CHH + c * 8] = z;
}

// ---- GEMM1 (fused x-convert + shift(H)): R7 structure + swizzled lsB ----
__global__ __launch_bounds__(256) void k_gemm1(const float* __restrict__ x,
                                               const f16* __restrict__ w1h,
                                               const float* __restrict__ fc1b,
                                               f16* __restrict__ h1p) {
  constexpr int LDA = 168;            // padded row stride (bank spread)
  __shared__ f16 lsA[128 * LDA];      // 43,008 B
  __shared__ f16 lsB[128 * 32];       // 8,192 B
  const int tid = threadIdx.x;
  const int lane = tid & 63, wave = tid >> 6;
  const int row0 = blockIdx.x * 128;
  const int wr = wave >> 1, wc = wave & 1;
  const int rl = lane & 15, kb = (lane >> 4) * 8;

  // stage A once: 128 rows x 160 cols, shift(H) fused, f32 -> f16
#pragma unroll
  for (int i = 0; i < 20; ++i) {
    int c = i * 256 + tid;            // 0..5119
    int row = c / 40;
    int q = c - row * 40;
    int ch0 = q * 4;
    int ks = ch0 >> 5;
    int s = ks - 2;
    int t = row0 + row;
    int h = (t >> 10) & 31;
    int hs = h - s;
    float4 v = {0.f, 0.f, 0.f, 0.f};
    if (hs >= 0 && hs < 32)
      v = *(const float4*)&x[(long)(t - s * 1024) * CIN + ch0];
    f16x4 o4;
    o4[0] = (f16)v.x; o4[1] = (f16)v.y; o4[2] = (f16)v.z; o4[3] = (f16)v.w;
    *(f16x4*)&lsA[row * LDA + ch0] = o4;
  }
  __syncthreads();

  for (int nt = 0; nt < 5; ++nt) {
    const int col0 = nt * 128;
    f32x4 acc[4][4] = {};
    for (int ks = 0; ks < 5; ++ks) {
#pragma unroll
      for (int issue = 0; issue < 2; ++issue) {
        int c = issue * 256 + tid;
        int br = c >> 2;
        int ju = (c & 3) ^ (br & 3);
        const f16* src = w1h + (size_t)(col0 + br) * CIN + ks * 32 + ju * 8;
        async16(src, (char*)lsB + issue * 4096 + wave * 1024);
      }
      __syncthreads();
      f16x8 af[4], bfr[4];
#pragma unroll
      for (int mi = 0; mi < 4; ++mi)
        af[mi] = *(const f16x8*)&lsA[(wr * 64 + mi * 16 + rl) * LDA + ks * 32 + kb];
#pragma unroll
      for (int ni = 0; ni < 4; ++ni) {
        int row = wc * 64 + ni * 16 + rl;
        int u = (lane >> 4) ^ (rl & 3);
        bfr[ni] = *(const f16x8*)&lsB[row * 32 + u * 8];
      }
#pragma unroll
      for (int mi = 0; mi < 4; ++mi)
#pragma unroll
        for (int ni = 0; ni < 4; ++ni)
          acc[mi][ni] = __builtin_amdgcn_mfma_f32_16x16x32_f16(af[mi], bfr[ni], acc[mi][ni], 0, 0, 0);
      __syncthreads();
    }
    const int rq = lane >> 4;
#pragma unroll
    for (int mi = 0; mi < 4; ++mi) {
      int rowq = row0 + wr * 64 + mi * 16 + rq * 4;
      int bq = rowq >> 15;
      int nq = rowq & 32767;
      int hq = nq >> 10, wq = (nq >> 5) & 31, dq = nq & 31;
      size_t pos = (size_t)((bq * PD + hq + 1) * PD + (wq + 1)) * PD + (dq + 1);
      f16* dst0 = h1p + pos * CHH;
#pragma unroll
      for (int ni = 0; ni < 4; ++ni) {
        int col = col0 + wc * 64 + ni * 16 + rl;
        float bias = fc1b[col];
#pragma unroll
        for (int r = 0; r < 4; ++r)
          dst0[(size_t)r * CHH + col] = (f16)(acc[mi][ni][r] + bias);
      }
    }
  }
}

// ---- depthwise 3x3x3 conv + bias + GELU (v12: R14 v9 body + forced 64-VGPR cap) ----
// __launch_bounds__(256, 8): 512/8 = 64-VGPR budget -> compiler must
// rematerialize wt from LDS instead of caching 36 regs; occupancy doubles.
__global__ __launch_bounds__(256, 8) void k_conv(const f16* __restrict__ h1p,
                                                 const f16* __restrict__ wTh,
                                                 const float* __restrict__ dwb,
                                                 f16* __restrict__ h2h) {
  __shared__ f16 lw[27 * 64];
  __shared__ f16 lb[64];
  const int tid = threadIdx.x;
  const int bid = blockIdx.x;          // 2560 = 8 * 320
  const int wg = (bid & 7) * 320 + (bid >> 3);
  const int cg = wg % 10;              // channel group, innermost
  const int oct = wg / 10;             // 0..255: 8-line group
#pragma unroll
  for (int i = 0; i < 7; ++i) {
    int idx = i * 256 + tid;
    if (idx < 27 * 64) lw[idx] = wTh[(idx >> 6) * CHH + cg * 64 + (idx & 63)];
  }
  if (tid < 64) lb[tid] = (f16)dwb[cg * 64 + tid];
  __syncthreads();

  const int lane = tid & 63, wave = tid >> 6;
  const int L0 = oct * 8 + wave * 2;   // even line; L1 = L0+1 same h,b
  const int c8 = lane & 7, dq = lane >> 3;
  const int d0 = dq * 4;
  const int ch0 = cg * 64 + c8 * 8;
  const int w0 = L0 & 31, h = (L0 >> 5) & 31, b = L0 >> 10;

  const size_t cidx = (size_t)((b * PD + h) * PD + w0) * PD + d0;
  const f16* base = h1p + cidx * CHH + ch0;

  f16x8 acc0[4], acc1[4];
  {
    f16x8 binit = *(const f16x8*)&lb[c8 * 8];
#pragma unroll
    for (int o = 0; o < 4; ++o) { acc0[o] = binit; acc1[o] = binit; }
  }

#pragma unroll
  for (int kz = 0; kz < 3; ++kz) {
    f16x8 wt[3][3];
#pragma unroll
    for (int ky = 0; ky < 3; ++ky)
#pragma unroll
      for (int kx = 0; kx < 3; ++kx)
        wt[ky][kx] = *(const f16x8*)&lw[((kz * 9 + ky * 3 + kx) << 6) + c8 * 8];
#pragma unroll
    for (int py = 0; py < 4; ++py) {
      const f16* pb = base + (size_t)(kz * PD + py) * PD * CHH;
      f16x8 v[6];
#pragma unroll
      for (int j = 0; j < 6; ++j)
        v[j] = *(const f16x8*)(pb + (size_t)j * CHH);
      if (py < 3) {
#pragma unroll
        for (int o = 0; o < 4; ++o)
#pragma unroll
          for (int kx = 0; kx < 3; ++kx)
            acc0[o] = v[o + kx] * wt[py][kx] + acc0[o];
      }
      if (py >= 1) {
#pragma unroll
        for (int o = 0; o < 4; ++o)
#pragma unroll
          for (int kx = 0; kx < 3; ++kx)
            acc1[o] = v[o + kx] * wt[py - 1][kx] + acc1[o];
      }
    }
  }

  const ptrdiff_t ob0 = (ptrdiff_t)(L0 * 32 + d0) * CHH + ch0;
  const ptrdiff_t ob1 = ob0 + (ptrdiff_t)32 * CHH;
#pragma unroll
  for (int o = 0; o < 4; ++o) {
    *(f16x8*)&h2h[ob0 + (ptrdiff_t)o * CHH] = gelu8(acc0[o]);
    *(f16x8*)&h2h[ob1 + (ptrdiff_t)o * CHH] = gelu8(acc1[o]);
  }
}

// ---- GEMM2 (R7 structure + XOR-swizzled LDS): shift(W) fused ----
__global__ __launch_bounds__(256) void k_gemm2(const f16* __restrict__ h2h,
                                               const f16* __restrict__ w2h,
                                               const float* __restrict__ fc2b,
                                               const f16* __restrict__ zp,
                                               float* __restrict__ out) {
  __shared__ f16 lsA[128 * 64];  // 16KB
  __shared__ f16 lsB[160 * 64];  // 20KB
  const int tid = threadIdx.x, lane = tid & 63, wave = tid >> 6;
  const int row0 = blockIdx.x * 128;
  const int rl = lane & 15;

  f32x4 acc[2][10] = {};

  for (int kt = 0; kt < 10; ++kt) {
    __syncthreads();
    const int k0 = kt * 64;
    const int s = (kt >> 1) - 2;  // W-shift for this 128-ch group
#pragma unroll
    for (int issue = 0; issue < 4; ++issue) {
      int c = issue * 256 + tid;
      int ar = c >> 3;
      int ju = (c & 7) ^ (ar & 7);      // swizzled source 16B-unit
      int kc = ju * 8;
      int t = row0 + ar;
      int w = (t >> 5) & 31;
      int wsv = w - s;
      const f16* src;
      if (wsv >= 0 && wsv < 32)
        src = h2h + (size_t)(t - s * 32) * CHH + k0 + kc;
      else
        src = zp + (size_t)(c & 63) * 8;
      async16(src, (char*)lsA + issue * 4096 + wave * 1024);
    }
#pragma unroll
    for (int issue = 0; issue < 5; ++issue) {
      int c = issue * 256 + tid;
      int br = c >> 3;
      int ju = (c & 7) ^ (br & 7);
      const f16* src = w2h + (size_t)br * CHH + k0 + ju * 8;
      async16(src, (char*)lsB + issue * 4096 + wave * 1024);
    }
    __syncthreads();
#pragma unroll
    for (int kk = 0; kk < 2; ++kk) {
      f16x8 af[2], bfr[10];
#pragma unroll
      for (int mi = 0; mi < 2; ++mi) {
        int row = wave * 32 + mi * 16 + rl;
        int u = (kk * 4 + (lane >> 4)) ^ (rl & 7);
        af[mi] = *(const f16x8*)&lsA[row * 64 + u * 8];
      }
#pragma unroll
      for (int ni = 0; ni < 10; ++ni) {
        int row = ni * 16 + rl;
        int u = (kk * 4 + (lane >> 4)) ^ (rl & 7);
        bfr[ni] = *(const f16x8*)&lsB[row * 64 + u * 8];
      }
#pragma unroll
      for (int mi = 0; mi < 2; ++mi)
#pragma unroll
        for (int ni = 0; ni < 10; ++ni)
          acc[mi][ni] = __builtin_amdgcn_mfma_f32_16x16x32_f16(af[mi], bfr[ni], acc[mi][ni], 0, 0, 0);
    }
  }
  const int rq = lane >> 4;
#pragma unroll
  for (int mi = 0; mi < 2; ++mi) {
#pragma unroll
    for (int ni = 0; ni < 10; ++ni) {
      int col = ni * 16 + rl;
      float bias = fc2b[col];
#pragma unroll
      for (int r = 0; r < 4; ++r) {
        int row = row0 + wave * 32 + mi * 16 + rq * 4 + r;
        out[(size_t)row * CIN + col] = acc[mi][ni][r] + bias;
      }
    }
  }
}

extern "C" void kernel_launch(void* const* d_in, const int* in_sizes, int n_in,
                              void* d_out, int out_size, void* d_ws, size_t ws_size,
                              hipStream_t stream) {
  const float* x    = (const float*)d_in[0];
  const float* fc1w = (const float*)d_in[1];
  const float* fc1b = (const float*)d_in[2];
  const float* dww  = (const float*)d_in[3];
  const float* dwb  = (const float*)d_in[4];
  const float* fc2w = (const float*)d_in[5];
  const float* fc2b = (const float*)d_in[6];

  char* ws = (char*)d_ws;
  f16* w1h  = (f16*)(ws + W1_OFF);
  f16* w2h  = (f16*)(ws + W2_OFF);
  f16* wTh  = (f16*)(ws + WTH_OFF);
  f16* zp   = (f16*)(ws + ZP_OFF);
  f16* h2h  = (f16*)(ws + U_OFF);
  f16* h1p  = (f16*)(ws + H1P_OFF);
  float* out = (float*)d_out;

  k_prep<<<PREPW_BLOCKS + SHELL_BLOCKS, 256, 0, stream>>>(
      fc1w, fc2w, dww, w1h, w2h, wTh, (unsigned*)zp, h1p);
  k_gemm1<<<512, 256, 0, stream>>>(x, w1h, fc1b, h1p);
  k_conv<<<2560, 256, 0, stream>>>(h1p, wTh, dwb, h2h);
  k_gemm2<<<512, 256, 0, stream>>>(h2h, w2h, fc2b, zp, out);
}

// Round 18
// 123.130 us; speedup vs baseline: 4.5006x; 4.5006x over previous
//
#include <hip/hip_runtime.h>
#include <hip/hip_bf16.h>
#include <hip/hip_fp16.h>
#include <math.h>

#define DEVI __device__ __forceinline__

typedef _Float16 f16;
typedef f16 f16x2 __attribute__((ext_vector_type(2)));
typedef f16 f16x4 __attribute__((ext_vector_type(4)));
typedef f16 f16x8 __attribute__((ext_vector_type(8)));
typedef float f32x4 __attribute__((ext_vector_type(4)));

// ---- problem dims (fixed) ----
constexpr int Bb = 2, Hh = 32, Ww = 32, Dd = 32;
constexpr int Nn = Hh * Ww * Dd;      // 32768
constexpr int BN = Bb * Nn;           // 65536 tokens
constexpr int CIN = 160, CHH = 640;
constexpr int PD = 34;                // padded dim
constexpr int PT = PD * PD * PD;      // 39304 padded tokens per batch

// ---- workspace layout (bytes) ----
constexpr size_t W1_OFF  = 0;                                   // fc1_w f16: 204,800
constexpr size_t W2_OFF  = W1_OFF + (size_t)CHH * CIN * 2;      // fc2_w f16: 204,800
constexpr size_t WTH_OFF = W2_OFF + (size_t)CIN * CHH * 2;      // dw_w f16 [27][640]: 34,560
constexpr size_t ZP_OFF  = WTH_OFF + 34816;                     // zero page: 8,192
constexpr size_t U_OFF   = 458752;                              // h2 f16: 83,886,080
constexpr size_t H1P_OFF = U_OFF + (size_t)BN * CHH * 2;        // h1 padded f16: 100,618,240

DEVI void async16(const void* g, void* l) {
  __builtin_amdgcn_global_load_lds(
      (const __attribute__((address_space(1))) void*)g,
      (__attribute__((address_space(3))) void*)l, 16, 0, 0);
}

// packed-f16 GELU (tanh form, div-free): g = x - x * rcp(1 + exp2(x*(C1+C2*x^2)))
DEVI f16x8 gelu8(f16x8 xa) {
  const __half2 C1 = __float2half2_rn(2.3022078f);
  const __half2 C2 = __float2half2_rn(0.102943324f);
  const __half2 ONE = __float2half2_rn(1.0f);
  f16x8 out;
#pragma unroll
  for (int j = 0; j < 8; j += 2) {
    __half2 xv = __builtin_bit_cast(__half2, f16x2{xa[j], xa[j + 1]});
    __half2 x2 = __hmul2(xv, xv);
    __half2 t  = __hfma2(x2, C2, C1);
    __half2 u  = __hmul2(xv, t);
    __half2 e  = h2exp2(u);
    __half2 r  = h2rcp(__hadd2(e, ONE));
    __half2 g  = __hsub2(xv, __hmul2(xv, r));
    f16x2 gg = __builtin_bit_cast(f16x2, g);
    out[j] = gg[0]; out[j + 1] = gg[1];
  }
  return out;
}

// ---- prep: weights -> f16, dw transpose, zero page (876 blocks only) ----
constexpr int PREPW_BLOCKS = 876;                       // 2*NW + 27*CHH + 2048
constexpr int NSHELL = 13072;                           // shell tokens total
constexpr int SHELL_CHUNKS = NSHELL * 80;               // 1,045,760 f16x8 chunks
constexpr int CPB = (SHELL_CHUNKS + 511) / 512;         // 2043 chunks per gemm1 block

__global__ __launch_bounds__(256) void k_prep(const float* __restrict__ fc1w,
                                              const float* __restrict__ fc2w,
                                              const float* __restrict__ dww,
                                              f16* __restrict__ w1h,
                                              f16* __restrict__ w2h,
                                              f16* __restrict__ wTh,
                                              unsigned* __restrict__ zp) {
  int i = blockIdx.x * 256 + threadIdx.x;
  const int NW = CHH * CIN;  // 102400
  if (i < NW) {
    w1h[i] = (f16)fc1w[i];
  } else if (i < 2 * NW) {
    w2h[i - NW] = (f16)fc2w[i - NW];
  } else if (i < 2 * NW + 27 * CHH) {
    int j = i - 2 * NW;
    int ch = j / 27, tap = j % 27;
    wTh[tap * CHH + ch] = (f16)dww[j];
  } else if (i < 2 * NW + 27 * CHH + 2048) {
    zp[i - (2 * NW + 27 * CHH)] = 0u;
  }
}

// shell chunk decode: chunk g -> (padded token p, channel chunk c)
DEVI bool shell_decode(int g, size_t& p, int& c) {
  int t = g / 80;
  c = g - t * 80;
  if (t >= NSHELL) return false;
  int b, hp, wp, dp;
  if (t < 4624) {                     // hp faces: [2][2][34][34]
    int i = t;
    b = i / 2312; i -= b * 2312;
    int f = i / 1156; i -= f * 1156;
    hp = f ? PD - 1 : 0;
    wp = i / 34; dp = i - (i / 34) * 34;
  } else if (t < 8976) {              // wp faces: [2][2][32][34], hp interior
    int i = t - 4624;
    b = i / 2176; i -= b * 2176;
    int f = i / 1088; i -= f * 1088;
    wp = f ? PD - 1 : 0;
    hp = 1 + i / 34; dp = i - (i / 34) * 34;
  } else {                            // dp faces: [2][2][32][32], hp,wp interior
    int i = t - 8976;
    b = i / 2048; i -= b * 2048;
    int f = i / 1024; i -= f * 1024;
    dp = f ? PD - 1 : 0;
    hp = 1 + i / 32; wp = 1 + (i & 31);
  }
  p = ((size_t)(b * PD + hp) * PD + wp) * PD + dp;
  return true;
}

// ---- GEMM1 (fused x-convert + shift(H)) + shell-zero preamble ----
__global__ __launch_bounds__(256) void k_gemm1(const float* __restrict__ x,
                                               const f16* __restrict__ w1h,
                                               const float* __restrict__ fc1b,
                                               f16* __restrict__ h1p) {
  constexpr int LDA = 168;            // padded row stride (bank spread)
  __shared__ f16 lsA[128 * LDA];      // 43,008 B
  __shared__ f16 lsB[128 * 32];       // 8,192 B
  const int tid = threadIdx.x;
  const int lane = tid & 63, wave = tid >> 6;
  const int row0 = blockIdx.x * 128;
  const int wr = wave >> 1, wc = wave & 1;
  const int rl = lane & 15, kb = (lane >> 4) * 8;

  // shell-zero preamble: this block's slice of the h1p pad shell.
  // Fire-and-forget stores; they drain in the background during staging.
  {
    const int g0 = blockIdx.x * CPB;
    const int g1 = min(g0 + CPB, SHELL_CHUNKS);
    f16x8 z = {};
    for (int g = g0 + tid; g < g1; g += 256) {
      size_t p; int c;
      if (shell_decode(g, p, c))
        *(f16x8*)&h1p[p * CHH + c * 8] = z;
    }
  }

  // stage A once: 128 rows x 160 cols, shift(H) fused, f32 -> f16
#pragma unroll
  for (int i = 0; i < 20; ++i) {
    int c = i * 256 + tid;            // 0..5119
    int row = c / 40;
    int q = c - row * 40;
    int ch0 = q * 4;
    int ks = ch0 >> 5;
    int s = ks - 2;
    int t = row0 + row;
    int h = (t >> 10) & 31;
    int hs = h - s;
    float4 v = {0.f, 0.f, 0.f, 0.f};
    if (hs >= 0 && hs < 32)
      v = *(const float4*)&x[(long)(t - s * 1024) * CIN + ch0];
    f16x4 o4;
    o4[0] = (f16)v.x; o4[1] = (f16)v.y; o4[2] = (f16)v.z; o4[3] = (f16)v.w;
    *(f16x4*)&lsA[row * LDA + ch0] = o4;
  }
  __syncthreads();

  for (int nt = 0; nt < 5; ++nt) {
    const int col0 = nt * 128;
    f32x4 acc[4][4] = {};
    for (int ks = 0; ks < 5; ++ks) {
#pragma unroll
      for (int issue = 0; issue < 2; ++issue) {
        int c = issue * 256 + tid;
        int br = c >> 2;
        int ju = (c & 3) ^ (br & 3);
        const f16* src = w1h + (size_t)(col0 + br) * CIN + ks * 32 + ju * 8;
        async16(src, (char*)lsB + issue * 4096 + wave * 1024);
      }
      __syncthreads();
      f16x8 af[4], bfr[4];
#pragma unroll
      for (int mi = 0; mi < 4; ++mi)
        af[mi] = *(const f16x8*)&lsA[(wr * 64 + mi * 16 + rl) * LDA + ks * 32 + kb];
#pragma unroll
      for (int ni = 0; ni < 4; ++ni) {
        int row = wc * 64 + ni * 16 + rl;
        int u = (lane >> 4) ^ (rl & 3);
        bfr[ni] = *(const f16x8*)&lsB[row * 32 + u * 8];
      }
#pragma unroll
      for (int mi = 0; mi < 4; ++mi)
#pragma unroll
        for (int ni = 0; ni < 4; ++ni)
          acc[mi][ni] = __builtin_amdgcn_mfma_f32_16x16x32_f16(af[mi], bfr[ni], acc[mi][ni], 0, 0, 0);
      __syncthreads();
    }
    const int rq = lane >> 4;
#pragma unroll
    for (int mi = 0; mi < 4; ++mi) {
      int rowq = row0 + wr * 64 + mi * 16 + rq * 4;
      int bq = rowq >> 15;
      int nq = rowq & 32767;
      int hq = nq >> 10, wq = (nq >> 5) & 31, dq = nq & 31;
      size_t pos = (size_t)((bq * PD + hq + 1) * PD + (wq + 1)) * PD + (dq + 1);
      f16* dst0 = h1p + pos * CHH;
#pragma unroll
      for (int ni = 0; ni < 4; ++ni) {
        int col = col0 + wc * 64 + ni * 16 + rl;
        float bias = fc1b[col];
#pragma unroll
        for (int r = 0; r < 4; ++r)
          dst0[(size_t)r * CHH + col] = (f16)(acc[mi][ni][r] + bias);
      }
    }
  }
}

// ---- depthwise 3x3x3 conv + bias + GELU (v9, R14 exact) ----
__global__ __launch_bounds__(256) void k_conv(const f16* __restrict__ h1p,
                                              const f16* __restrict__ wTh,
                                              const float* __restrict__ dwb,
                                              f16* __restrict__ h2h) {
  __shared__ f16 lw[27 * 64];
  __shared__ f16 lb[64];
  const int tid = threadIdx.x;
  const int bid = blockIdx.x;          // 2560 = 8 * 320
  const int wg = (bid & 7) * 320 + (bid >> 3);
  const int cg = wg % 10;              // channel group, innermost
  const int oct = wg / 10;             // 0..255: 8-line group
#pragma unroll
  for (int i = 0; i < 7; ++i) {
    int idx = i * 256 + tid;
    if (idx < 27 * 64) lw[idx] = wTh[(idx >> 6) * CHH + cg * 64 + (idx & 63)];
  }
  if (tid < 64) lb[tid] = (f16)dwb[cg * 64 + tid];
  __syncthreads();

  const int lane = tid & 63, wave = tid >> 6;
  const int L0 = oct * 8 + wave * 2;   // even line; L1 = L0+1 same h,b
  const int c8 = lane & 7, dq = lane >> 3;
  const int d0 = dq * 4;
  const int ch0 = cg * 64 + c8 * 8;
  const int w0 = L0 & 31, h = (L0 >> 5) & 31, b = L0 >> 10;

  const size_t cidx = (size_t)((b * PD + h) * PD + w0) * PD + d0;
  const f16* base = h1p + cidx * CHH + ch0;

  f16x8 acc0[4], acc1[4];
  {
    f16x8 binit = *(const f16x8*)&lb[c8 * 8];
#pragma unroll
    for (int o = 0; o < 4; ++o) { acc0[o] = binit; acc1[o] = binit; }
  }

#pragma unroll
  for (int kz = 0; kz < 3; ++kz) {
    f16x8 wt[3][3];
#pragma unroll
    for (int ky = 0; ky < 3; ++ky)
#pragma unroll
      for (int kx = 0; kx < 3; ++kx)
        wt[ky][kx] = *(const f16x8*)&lw[((kz * 9 + ky * 3 + kx) << 6) + c8 * 8];
#pragma unroll
    for (int py = 0; py < 4; ++py) {
      const f16* pb = base + (size_t)(kz * PD + py) * PD * CHH;
      f16x8 v[6];
#pragma unroll
      for (int j = 0; j < 6; ++j)
        v[j] = *(const f16x8*)(pb + (size_t)j * CHH);
      if (py < 3) {
#pragma unroll
        for (int o = 0; o < 4; ++o)
#pragma unroll
          for (int kx = 0; kx < 3; ++kx)
            acc0[o] = v[o + kx] * wt[py][kx] + acc0[o];
      }
      if (py >= 1) {
#pragma unroll
        for (int o = 0; o < 4; ++o)
#pragma unroll
          for (int kx = 0; kx < 3; ++kx)
            acc1[o] = v[o + kx] * wt[py - 1][kx] + acc1[o];
      }
    }
  }

  const ptrdiff_t ob0 = (ptrdiff_t)(L0 * 32 + d0) * CHH + ch0;
  const ptrdiff_t ob1 = ob0 + (ptrdiff_t)32 * CHH;
#pragma unroll
  for (int o = 0; o < 4; ++o) {
    *(f16x8*)&h2h[ob0 + (ptrdiff_t)o * CHH] = gelu8(acc0[o]);
    *(f16x8*)&h2h[ob1 + (ptrdiff_t)o * CHH] = gelu8(acc1[o]);
  }
}

// ---- GEMM2 (R7 structure + XOR-swizzled LDS): shift(W) fused ----
__global__ __launch_bounds__(256) void k_gemm2(const f16* __restrict__ h2h,
                                               const f16* __restrict__ w2h,
                                               const float* __restrict__ fc2b,
                                               const f16* __restrict__ zp,
                                               float* __restrict__ out) {
  __shared__ f16 lsA[128 * 64];  // 16KB
  __shared__ f16 lsB[160 * 64];  // 20KB
  const int tid = threadIdx.x, lane = tid & 63, wave = tid >> 6;
  const int row0 = blockIdx.x * 128;
  const int rl = lane & 15;

  f32x4 acc[2][10] = {};

  for (int kt = 0; kt < 10; ++kt) {
    __syncthreads();
    const int k0 = kt * 64;
    const int s = (kt >> 1) - 2;  // W-shift for this 128-ch group
#pragma unroll
    for (int issue = 0; issue < 4; ++issue) {
      int c = issue * 256 + tid;
      int ar = c >> 3;
      int ju = (c & 7) ^ (ar & 7);      // swizzled source 16B-unit
      int kc = ju * 8;
      int t = row0 + ar;
      int w = (t >> 5) & 31;
      int wsv = w - s;
      const f16* src;
      if (wsv >= 0 && wsv < 32)
        src = h2h + (size_t)(t - s * 32) * CHH + k0 + kc;
      else
        src = zp + (size_t)(c & 63) * 8;
      async16(src, (char*)lsA + issue * 4096 + wave * 1024);
    }
#pragma unroll
    for (int issue = 0; issue < 5; ++issue) {
      int c = issue * 256 + tid;
      int br = c >> 3;
      int ju = (c & 7) ^ (br & 7);
      const f16* src = w2h + (size_t)br * CHH + k0 + ju * 8;
      async16(src, (char*)lsB + issue * 4096 + wave * 1024);
    }
    __syncthreads();
#pragma unroll
    for (int kk = 0; kk < 2; ++kk) {
      f16x8 af[2], bfr[10];
#pragma unroll
      for (int mi = 0; mi < 2; ++mi) {
        int row = wave * 32 + mi * 16 + rl;
        int u = (kk * 4 + (lane >> 4)) ^ (rl & 7);
        af[mi] = *(const f16x8*)&lsA[row * 64 + u * 8];
      }
#pragma unroll
      for (int ni = 0; ni < 10; ++ni) {
        int row = ni * 16 + rl;
        int u = (kk * 4 + (lane >> 4)) ^ (rl & 7);
        bfr[ni] = *(const f16x8*)&lsB[row * 64 + u * 8];
      }
#pragma unroll
      for (int mi = 0; mi < 2; ++mi)
#pragma unroll
        for (int ni = 0; ni < 10; ++ni)
          acc[mi][ni] = __builtin_amdgcn_mfma_f32_16x16x32_f16(af[mi], bfr[ni], acc[mi][ni], 0, 0, 0);
    }
  }
  const int rq = lane >> 4;
#pragma unroll
  for (int mi = 0; mi < 2; ++mi) {
#pragma unroll
    for (int ni = 0; ni < 10; ++ni) {
      int col = ni * 16 + rl;
      float bias = fc2b[col];
#pragma unroll
      for (int r = 0; r < 4; ++r) {
        int row = row0 + wave * 32 + mi * 16 + rq * 4 + r;
        out[(size_t)row * CIN + col] = acc[mi][ni][r] + bias;
      }
    }
  }
}

extern "C" void kernel_launch(void* const* d_in, const int* in_sizes, int n_in,
                              void* d_out, int out_size, void* d_ws, size_t ws_size,
                              hipStream_t stream) {
  const float* x    = (const float*)d_in[0];
  const float* fc1w = (const float*)d_in[1];
  const float* fc1b = (const float*)d_in[2];
  const float* dww  = (const float*)d_in[3];
  const float* dwb  = (const float*)d_in[4];
  const float* fc2w = (const float*)d_in[5];
  const float* fc2b = (const float*)d_in[6];

  char* ws = (char*)d_ws;
  f16* w1h  = (f16*)(ws + W1_OFF);
  f16* w2h  = (f16*)(ws + W2_OFF);
  f16* wTh  = (f16*)(ws + WTH_OFF);
  f16* zp   = (f16*)(ws + ZP_OFF);
  f16* h2h  = (f16*)(ws + U_OFF);
  f16* h1p  = (f16*)(ws + H1P_OFF);
  float* out = (float*)d_out;

  k_prep<<<PREPW_BLOCKS, 256, 0, stream>>>(
      fc1w, fc2w, dww, w1h, w2h, wTh, (unsigned*)zp);
  k_gemm1<<<512, 256, 0, stream>>>(x, w1h, fc1b, h1p);
  k_conv<<<2560, 256, 0, stream>>>(h1p, wTh, dwb, h2h);
  k_gemm2<<<512, 256, 0, stream>>>(h2h, w2h, fc2b, zp, out);
}

// Round 19
// 120.649 us; speedup vs baseline: 4.5932x; 1.0206x over previous
//
#include <hip/hip_runtime.h>
#include <hip/hip_bf16.h>
#include <hip/hip_fp16.h>
#include <math.h>

#define DEVI __device__ __forceinline__

typedef _Float16 f16;
typedef f16 f16x2 __attribute__((ext_vector_type(2)));
typedef f16 f16x4 __attribute__((ext_vector_type(4)));
typedef f16 f16x8 __attribute__((ext_vector_type(8)));
typedef float f32x4 __attribute__((ext_vector_type(4)));

// ---- problem dims (fixed) ----
constexpr int Bb = 2, Hh = 32, Ww = 32, Dd = 32;
constexpr int Nn = Hh * Ww * Dd;      // 32768
constexpr int BN = Bb * Nn;           // 65536 tokens
constexpr int CIN = 160, CHH = 640;
constexpr int PD = 34;                // padded dim
constexpr int PT = PD * PD * PD;      // 39304 padded tokens per batch

// ---- workspace layout (bytes) ----
constexpr size_t W1_OFF  = 0;                                   // fc1_w f16: 204,800
constexpr size_t W2_OFF  = W1_OFF + (size_t)CHH * CIN * 2;      // fc2_w f16: 204,800
constexpr size_t WTH_OFF = W2_OFF + (size_t)CIN * CHH * 2;      // dw_w f16 [27][640]: 34,560
constexpr size_t ZP_OFF  = WTH_OFF + 34816;                     // zero page: 8,192
constexpr size_t U_OFF   = 458752;                              // h2 f16: 83,886,080
constexpr size_t H1P_OFF = U_OFF + (size_t)BN * CHH * 2;        // h1 padded f16: 100,618,240

DEVI void async16(const void* g, void* l) {
  __builtin_amdgcn_global_load_lds(
      (const __attribute__((address_space(1))) void*)g,
      (__attribute__((address_space(3))) void*)l, 16, 0, 0);
}

// packed-f16 GELU (tanh form, div-free): g = x - x * rcp(1 + exp2(x*(C1+C2*x^2)))
DEVI f16x8 gelu8(f16x8 xa) {
  const __half2 C1 = __float2half2_rn(2.3022078f);
  const __half2 C2 = __float2half2_rn(0.102943324f);
  const __half2 ONE = __float2half2_rn(1.0f);
  f16x8 out;
#pragma unroll
  for (int j = 0; j < 8; j += 2) {
    __half2 xv = __builtin_bit_cast(__half2, f16x2{xa[j], xa[j + 1]});
    __half2 x2 = __hmul2(xv, xv);
    __half2 t  = __hfma2(x2, C2, C1);
    __half2 u  = __hmul2(xv, t);
    __half2 e  = h2exp2(u);
    __half2 r  = h2rcp(__hadd2(e, ONE));
    __half2 g  = __hsub2(xv, __hmul2(xv, r));
    f16x2 gg = __builtin_bit_cast(f16x2, g);
    out[j] = gg[0]; out[j + 1] = gg[1];
  }
  return out;
}

// ---- prep (merged): weights -> f16, dw transpose, zero page, h1p shell faces ----
constexpr int PREPW_BLOCKS = 876;                       // 2*NW + 27*CHH + 2048
constexpr int NSHELL = 13072;                           // shell tokens total
constexpr int SHELL_BLOCKS = (NSHELL * 80 + 255) / 256; // 4085

__global__ __launch_bounds__(256) void k_prep(const float* __restrict__ fc1w,
                                              const float* __restrict__ fc2w,
                                              const float* __restrict__ dww,
                                              f16* __restrict__ w1h,
                                              f16* __restrict__ w2h,
                                              f16* __restrict__ wTh,
                                              unsigned* __restrict__ zp,
                                              f16* __restrict__ h1p) {
  const int bid = blockIdx.x;
  const int tid = threadIdx.x;
  if (bid < PREPW_BLOCKS) {
    int i = bid * 256 + tid;
    const int NW = CHH * CIN;  // 102400
    if (i < NW) {
      w1h[i] = (f16)fc1w[i];
    } else if (i < 2 * NW) {
      w2h[i - NW] = (f16)fc2w[i - NW];
    } else if (i < 2 * NW + 27 * CHH) {
      int j = i - 2 * NW;
      int ch = j / 27, tap = j % 27;
      wTh[tap * CHH + ch] = (f16)dww[j];
    } else if (i < 2 * NW + 27 * CHH + 2048) {
      zp[i - (2 * NW + 27 * CHH)] = 0u;
    }
    return;
  }
  // shell faces: thread per (shell token, 8-ch chunk), chunk fastest -> coalesced
  int g = (bid - PREPW_BLOCKS) * 256 + tid;
  int t = g / 80;
  int c = g - t * 80;
  if (t >= NSHELL) return;
  int b, hp, wp, dp;
  if (t < 4624) {                     // hp faces: [2][2][34][34]
    int i = t;
    b = i / 2312; i -= b * 2312;
    int f = i / 1156; i -= f * 1156;
    hp = f ? PD - 1 : 0;
    wp = i / 34; dp = i - (i / 34) * 34;
  } else if (t < 8976) {              // wp faces: [2][2][32][34], hp interior
    int i = t - 4624;
    b = i / 2176; i -= b * 2176;
    int f = i / 1088; i -= f * 1088;
    wp = f ? PD - 1 : 0;
    hp = 1 + i / 34; dp = i - (i / 34) * 34;
  } else {                            // dp faces: [2][2][32][32], hp,wp interior
    int i = t - 8976;
    b = i / 2048; i -= b * 2048;
    int f = i / 1024; i -= f * 1024;
    dp = f ? PD - 1 : 0;
    hp = 1 + i / 32; wp = 1 + (i & 31);
  }
  size_t p = ((size_t)(b * PD + hp) * PD + wp) * PD + dp;
  f16x8 z = {};
  *(f16x8*)&h1p[p * CHH + c * 8] = z;
}

// ---- GEMM1 (fused x-convert + shift(H)): R7 structure + swizzled lsB ----
__global__ __launch_bounds__(256) void k_gemm1(const float* __restrict__ x,
                                               const f16* __restrict__ w1h,
                                               const float* __restrict__ fc1b,
                                               f16* __restrict__ h1p) {
  constexpr int LDA = 168;            // padded row stride (bank spread)
  __shared__ f16 lsA[128 * LDA];      // 43,008 B
  __shared__ f16 lsB[128 * 32];       // 8,192 B
  const int tid = threadIdx.x;
  const int lane = tid & 63, wave = tid >> 6;
  const int row0 = blockIdx.x * 128;
  const int wr = wave >> 1, wc = wave & 1;
  const int rl = lane & 15, kb = (lane >> 4) * 8;

  // stage A once: 128 rows x 160 cols, shift(H) fused, f32 -> f16
#pragma unroll
  for (int i = 0; i < 20; ++i) {
    int c = i * 256 + tid;            // 0..5119
    int row = c / 40;
    int q = c - row * 40;
    int ch0 = q * 4;
    int ks = ch0 >> 5;
    int s = ks - 2;
    int t = row0 + row;
    int h = (t >> 10) & 31;
    int hs = h - s;
    float4 v = {0.f, 0.f, 0.f, 0.f};
    if (hs >= 0 && hs < 32)
      v = *(const float4*)&x[(long)(t - s * 1024) * CIN + ch0];
    f16x4 o4;
    o4[0] = (f16)v.x; o4[1] = (f16)v.y; o4[2] = (f16)v.z; o4[3] = (f16)v.w;
    *(f16x4*)&lsA[row * LDA + ch0] = o4;
  }
  __syncthreads();

  for (int nt = 0; nt < 5; ++nt) {
    const int col0 = nt * 128;
    f32x4 acc[4][4] = {};
    for (int ks = 0; ks < 5; ++ks) {
#pragma unroll
      for (int issue = 0; issue < 2; ++issue) {
        int c = issue * 256 + tid;
        int br = c >> 2;
        int ju = (c & 3) ^ (br & 3);
        const f16* src = w1h + (size_t)(col0 + br) * CIN + ks * 32 + ju * 8;
        async16(src, (char*)lsB + issue * 4096 + wave * 1024);
      }
      __syncthreads();
      f16x8 af[4], bfr[4];
#pragma unroll
      for (int mi = 0; mi < 4; ++mi)
        af[mi] = *(const f16x8*)&lsA[(wr * 64 + mi * 16 + rl) * LDA + ks * 32 + kb];
#pragma unroll
      for (int ni = 0; ni < 4; ++ni) {
        int row = wc * 64 + ni * 16 + rl;
        int u = (lane >> 4) ^ (rl & 3);
        bfr[ni] = *(const f16x8*)&lsB[row * 32 + u * 8];
      }
#pragma unroll
      for (int mi = 0; mi < 4; ++mi)
#pragma unroll
        for (int ni = 0; ni < 4; ++ni)
          acc[mi][ni] = __builtin_amdgcn_mfma_f32_16x16x32_f16(af[mi], bfr[ni], acc[mi][ni], 0, 0, 0);
      __syncthreads();
    }
    const int rq = lane >> 4;
#pragma unroll
    for (int mi = 0; mi < 4; ++mi) {
      int rowq = row0 + wr * 64 + mi * 16 + rq * 4;
      int bq = rowq >> 15;
      int nq = rowq & 32767;
      int hq = nq >> 10, wq = (nq >> 5) & 31, dq = nq & 31;
      size_t pos = (size_t)((bq * PD + hq + 1) * PD + (wq + 1)) * PD + (dq + 1);
      f16* dst0 = h1p + pos * CHH;
#pragma unroll
      for (int ni = 0; ni < 4; ++ni) {
        int col = col0 + wc * 64 + ni * 16 + rl;
        float bias = fc1b[col];
#pragma unroll
        for (int r = 0; r < 4; ++r)
          dst0[(size_t)r * CHH + col] = (f16)(acc[mi][ni][r] + bias);
      }
    }
  }
}

// ---- depthwise 3x3x3 conv + bias + GELU (v9: 2 w-lines/wave, f16 gelu) ----
__global__ __launch_bounds__(256) void k_conv(const f16* __restrict__ h1p,
                                              const f16* __restrict__ wTh,
                                              const float* __restrict__ dwb,
                                              f16* __restrict__ h2h) {
  __shared__ f16 lw[27 * 64];
  __shared__ f16 lb[64];
  const int tid = threadIdx.x;
  const int bid = blockIdx.x;          // 2560 = 8 * 320
  const int wg = (bid & 7) * 320 + (bid >> 3);
  const int cg = wg % 10;              // channel group, innermost
  const int oct = wg / 10;             // 0..255: 8-line group
#pragma unroll
  for (int i = 0; i < 7; ++i) {
    int idx = i * 256 + tid;
    if (idx < 27 * 64) lw[idx] = wTh[(idx >> 6) * CHH + cg * 64 + (idx & 63)];
  }
  if (tid < 64) lb[tid] = (f16)dwb[cg * 64 + tid];
  __syncthreads();

  const int lane = tid & 63, wave = tid >> 6;
  const int L0 = oct * 8 + wave * 2;   // even line; L1 = L0+1 same h,b
  const int c8 = lane & 7, dq = lane >> 3;
  const int d0 = dq * 4;
  const int ch0 = cg * 64 + c8 * 8;
  const int w0 = L0 & 31, h = (L0 >> 5) & 31, b = L0 >> 10;

  const size_t cidx = (size_t)((b * PD + h) * PD + w0) * PD + d0;
  const f16* base = h1p + cidx * CHH + ch0;

  f16x8 acc0[4], acc1[4];
  {
    f16x8 binit = *(const f16x8*)&lb[c8 * 8];
#pragma unroll
    for (int o = 0; o < 4; ++o) { acc0[o] = binit; acc1[o] = binit; }
  }

#pragma unroll
  for (int kz = 0; kz < 3; ++kz) {
    f16x8 wt[3][3];
#pragma unroll
    for (int ky = 0; ky < 3; ++ky)
#pragma unroll
      for (int kx = 0; kx < 3; ++kx)
        wt[ky][kx] = *(const f16x8*)&lw[((kz * 9 + ky * 3 + kx) << 6) + c8 * 8];
#pragma unroll
    for (int py = 0; py < 4; ++py) {
      const f16* pb = base + (size_t)(kz * PD + py) * PD * CHH;
      f16x8 v[6];
#pragma unroll
      for (int j = 0; j < 6; ++j)
        v[j] = *(const f16x8*)(pb + (size_t)j * CHH);
      if (py < 3) {
#pragma unroll
        for (int o = 0; o < 4; ++o)
#pragma unroll
          for (int kx = 0; kx < 3; ++kx)
            acc0[o] = v[o + kx] * wt[py][kx] + acc0[o];
      }
      if (py >= 1) {
#pragma unroll
        for (int o = 0; o < 4; ++o)
#pragma unroll
          for (int kx = 0; kx < 3; ++kx)
            acc1[o] = v[o + kx] * wt[py - 1][kx] + acc1[o];
      }
    }
  }

  const ptrdiff_t ob0 = (ptrdiff_t)(L0 * 32 + d0) * CHH + ch0;
  const ptrdiff_t ob1 = ob0 + (ptrdiff_t)32 * CHH;
#pragma unroll
  for (int o = 0; o < 4; ++o) {
    *(f16x8*)&h2h[ob0 + (ptrdiff_t)o * CHH] = gelu8(acc0[o]);
    *(f16x8*)&h2h[ob1 + (ptrdiff_t)o * CHH] = gelu8(acc1[o]);
  }
}

// ---- GEMM2 (R7 structure + XOR-swizzled LDS): shift(W) fused ----
__global__ __launch_bounds__(256) void k_gemm2(const f16* __restrict__ h2h,
                                               const f16* __restrict__ w2h,
                                               const float* __restrict__ fc2b,
                                               const f16* __restrict__ zp,
                                               float* __restrict__ out) {
  __shared__ f16 lsA[128 * 64];  // 16KB
  __shared__ f16 lsB[160 * 64];  // 20KB
  const int tid = threadIdx.x, lane = tid & 63, wave = tid >> 6;
  const int row0 = blockIdx.x * 128;
  const int rl = lane & 15;

  f32x4 acc[2][10] = {};

  for (int kt = 0; kt < 10; ++kt) {
    __syncthreads();
    const int k0 = kt * 64;
    const int s = (kt >> 1) - 2;  // W-shift for this 128-ch group
#pragma unroll
    for (int issue = 0; issue < 4; ++issue) {
      int c = issue * 256 + tid;
      int ar = c >> 3;
      int ju = (c & 7) ^ (ar & 7);      // swizzled source 16B-unit
      int kc = ju * 8;
      int t = row0 + ar;
      int w = (t >> 5) & 31;
      int wsv = w - s;
      const f16* src;
      if (wsv >= 0 && wsv < 32)
        src = h2h + (size_t)(t - s * 32) * CHH + k0 + kc;
      else
        src = zp + (size_t)(c & 63) * 8;
      async16(src, (char*)lsA + issue * 4096 + wave * 1024);
    }
#pragma unroll
    for (int issue = 0; issue < 5; ++issue) {
      int c = issue * 256 + tid;
      int br = c >> 3;
      int ju = (c & 7) ^ (br & 7);
      const f16* src = w2h + (size_t)br * CHH + k0 + ju * 8;
      async16(src, (char*)lsB + issue * 4096 + wave * 1024);
    }
    __syncthreads();
#pragma unroll
    for (int kk = 0; kk < 2; ++kk) {
      f16x8 af[2], bfr[10];
#pragma unroll
      for (int mi = 0; mi < 2; ++mi) {
        int row = wave * 32 + mi * 16 + rl;
        int u = (kk * 4 + (lane >> 4)) ^ (rl & 7);
        af[mi] = *(const f16x8*)&lsA[row * 64 + u * 8];
      }
#pragma unroll
      for (int ni = 0; ni < 10; ++ni) {
        int row = ni * 16 + rl;
        int u = (kk * 4 + (lane >> 4)) ^ (rl & 7);
        bfr[ni] = *(const f16x8*)&lsB[row * 64 + u * 8];
      }
#pragma unroll
      for (int mi = 0; mi < 2; ++mi)
#pragma unroll
        for (int ni = 0; ni < 10; ++ni)
          acc[mi][ni] = __builtin_amdgcn_mfma_f32_16x16x32_f16(af[mi], bfr[ni], acc[mi][ni], 0, 0, 0);
    }
  }
  const int rq = lane >> 4;
#pragma unroll
  for (int mi = 0; mi < 2; ++mi) {
#pragma unroll
    for (int ni = 0; ni < 10; ++ni) {
      int col = ni * 16 + rl;
      float bias = fc2b[col];
#pragma unroll
      for (int r = 0; r < 4; ++r) {
        int row = row0 + wave * 32 + mi * 16 + rq * 4 + r;
        out[(size_t)row * CIN + col] = acc[mi][ni][r] + bias;
      }
    }
  }
}

extern "C" void kernel_launch(void* const* d_in, const int* in_sizes, int n_in,
                              void* d_out, int out_size, void* d_ws, size_t ws_size,
                              hipStream_t stream) {
  const float* x    = (const float*)d_in[0];
  const float* fc1w = (const float*)d_in[1];
  const float* fc1b = (const float*)d_in[2];
  const float* dww  = (const float*)d_in[3];
  const float* dwb  = (const float*)d_in[4];
  const float* fc2w = (const float*)d_in[5];
  const float* fc2b = (const float*)d_in[6];

  char* ws = (char*)d_ws;
  f16* w1h  = (f16*)(ws + W1_OFF);
  f16* w2h  = (f16*)(ws + W2_OFF);
  f16* wTh  = (f16*)(ws + WTH_OFF);
  f16* zp   = (f16*)(ws + ZP_OFF);
  f16* h2h  = (f16*)(ws + U_OFF);
  f16* h1p  = (f16*)(ws + H1P_OFF);
  float* out = (float*)d_out;

  k_prep<<<PREPW_BLOCKS + SHELL_BLOCKS, 256, 0, stream>>>(
      fc1w, fc2w, dww, w1h, w2h, wTh, (unsigned*)zp, h1p);
  k_gemm1<<<512, 256, 0, stream>>>(x, w1h, fc1b, h1p);
  k_conv<<<2560, 256, 0, stream>>>(h1p, wTh, dwb, h2h);
  k_gemm2<<<512, 256, 0, stream>>>(h2h, w2h, fc2b, zp, out);
}